// Round 1
// baseline (145.502 us; speedup 1.0000x reference)
//
#include <hip/hip_runtime.h>
#include <stdint.h>

#define D_DIM 1024
#define N_DIM 65536
#define BIN   16
#define Q_DIM 2048
#define K_DIM 3

#define NBLK  256          // one block per CU
#define NT    64           // n-columns per tile
#define TILES 4            // 4 tiles -> 256 n per block
#define TPB   1024
#define LDS_BYTES (D_DIM * 128)   // 1024 rows x 64 bf16 = 131072 B

// round-to-nearest-even f32 -> bf16 (values are positive normal probs; no NaN/Inf)
__device__ __forceinline__ uint32_t f2bf(float f) {
    uint32_t u = __float_as_uint(f);
    return (u + 0x7fffu + ((u >> 16) & 1u)) >> 16;
}

template<bool ATOMIC>
__global__ __launch_bounds__(TPB) void rap_main(const float* __restrict__ W,
                                                const int* __restrict__ qidx,
                                                float* __restrict__ outp) {
    extern __shared__ char smem[];
    const int tid = threadIdx.x;
    const int bid = blockIdx.x;

    // ---- per-thread query constants (2 queries/thread) ----
    const int q0 = tid * 2;
    int baseb[2][K_DIM];   // d*128 : byte base of LDS row
    int swzb[2][K_DIM];    // (d&15)*8 : qword XOR swizzle in bytes
#pragma unroll
    for (int qq = 0; qq < 2; ++qq) {
#pragma unroll
        for (int k = 0; k < K_DIM; ++k) {
            const int d = qidx[(q0 + qq) * K_DIM + k];
            baseb[qq][k] = d << 7;
            swzb[qq][k]  = (d & 15) << 3;
        }
    }

    // ---- staging mapping: thread -> (group g, n-quad nq) ----
    const int g  = tid >> 4;     // 0..63
    const int nq = tid & 15;     // 0..15 (4 n's each)
    const int n_base = bid * (NT * TILES) + nq * 4;

    float acc0 = 0.f, acc1 = 0.f;
    float4 e[BIN];

    // prologue: issue tile-0 loads
    {
        const float4* wp = (const float4*)(W + (size_t)(g * BIN) * N_DIM + n_base);
#pragma unroll
        for (int b = 0; b < BIN; ++b) e[b] = wp[b * (N_DIM / 4)];
    }

    for (int t = 0; t < TILES; ++t) {
        // ---- normalize staged regs, write bf16 probs to LDS (swizzled) ----
        {
#pragma unroll
            for (int b = 0; b < BIN; ++b) {
                e[b].x = __expf(e[b].x);
                e[b].y = __expf(e[b].y);
                e[b].z = __expf(e[b].z);
                e[b].w = __expf(e[b].w);
            }
            float sx = e[0].x, sy = e[0].y, sz = e[0].z, sw = e[0].w;
#pragma unroll
            for (int b = 1; b < BIN; ++b) { sx += e[b].x; sy += e[b].y; sz += e[b].z; sw += e[b].w; }
            const float rx = __builtin_amdgcn_rcpf(sx);
            const float ry = __builtin_amdgcn_rcpf(sy);
            const float rz = __builtin_amdgcn_rcpf(sz);
            const float rw = __builtin_amdgcn_rcpf(sw);
#pragma unroll
            for (int b = 0; b < BIN; ++b) {
                const int d = g * BIN + b;
                const uint32_t lo = f2bf(e[b].x * rx) | (f2bf(e[b].y * ry) << 16);
                const uint32_t hi = f2bf(e[b].z * rz) | (f2bf(e[b].w * rw) << 16);
                uint2 v; v.x = lo; v.y = hi;
                *(uint2*)(smem + (d << 7) + ((nq ^ (d & 15)) << 3)) = v;
            }
        }
        __syncthreads();

        // ---- issue next tile's global loads early (hide HBM under compute) ----
        if (t + 1 < TILES) {
            const float4* wp = (const float4*)(W + (size_t)(g * BIN) * N_DIM
                                               + (n_base + (t + 1) * NT));
#pragma unroll
            for (int b = 0; b < BIN; ++b) e[b] = wp[b * (N_DIM / 4)];
        }

        // ---- compute: 2 queries, 16 qword-iterations (4 n each) ----
#pragma unroll
        for (int j = 0; j < 16; ++j) {
            const int j8 = j << 3;
            const uint2 va0 = *(const uint2*)(smem + baseb[0][0] + (j8 ^ swzb[0][0]));
            const uint2 vb0 = *(const uint2*)(smem + baseb[0][1] + (j8 ^ swzb[0][1]));
            const uint2 vc0 = *(const uint2*)(smem + baseb[0][2] + (j8 ^ swzb[0][2]));
            const uint2 va1 = *(const uint2*)(smem + baseb[1][0] + (j8 ^ swzb[1][0]));
            const uint2 vb1 = *(const uint2*)(smem + baseb[1][1] + (j8 ^ swzb[1][1]));
            const uint2 vc1 = *(const uint2*)(smem + baseb[1][2] + (j8 ^ swzb[1][2]));
            {
                const float a0 = __uint_as_float(va0.x << 16), a1 = __uint_as_float(va0.x & 0xffff0000u);
                const float a2 = __uint_as_float(va0.y << 16), a3 = __uint_as_float(va0.y & 0xffff0000u);
                const float b0 = __uint_as_float(vb0.x << 16), b1 = __uint_as_float(vb0.x & 0xffff0000u);
                const float b2 = __uint_as_float(vb0.y << 16), b3 = __uint_as_float(vb0.y & 0xffff0000u);
                const float c0 = __uint_as_float(vc0.x << 16), c1 = __uint_as_float(vc0.x & 0xffff0000u);
                const float c2 = __uint_as_float(vc0.y << 16), c3 = __uint_as_float(vc0.y & 0xffff0000u);
                acc0 = fmaf(a0 * b0, c0, acc0);
                acc0 = fmaf(a1 * b1, c1, acc0);
                acc0 = fmaf(a2 * b2, c2, acc0);
                acc0 = fmaf(a3 * b3, c3, acc0);
            }
            {
                const float a0 = __uint_as_float(va1.x << 16), a1 = __uint_as_float(va1.x & 0xffff0000u);
                const float a2 = __uint_as_float(va1.y << 16), a3 = __uint_as_float(va1.y & 0xffff0000u);
                const float b0 = __uint_as_float(vb1.x << 16), b1 = __uint_as_float(vb1.x & 0xffff0000u);
                const float b2 = __uint_as_float(vb1.y << 16), b3 = __uint_as_float(vb1.y & 0xffff0000u);
                const float c0 = __uint_as_float(vc1.x << 16), c1 = __uint_as_float(vc1.x & 0xffff0000u);
                const float c2 = __uint_as_float(vc1.y << 16), c3 = __uint_as_float(vc1.y & 0xffff0000u);
                acc1 = fmaf(a0 * b0, c0, acc1);
                acc1 = fmaf(a1 * b1, c1, acc1);
                acc1 = fmaf(a2 * b2, c2, acc1);
                acc1 = fmaf(a3 * b3, c3, acc1);
            }
        }
        __syncthreads();
    }

    if (ATOMIC) {
        atomicAdd(outp + q0,     acc0 * (1.0f / N_DIM));
        atomicAdd(outp + q0 + 1, acc1 * (1.0f / N_DIM));
    } else {
        outp[(size_t)bid * Q_DIM + q0]     = acc0;
        outp[(size_t)bid * Q_DIM + q0 + 1] = acc1;
    }
}

__global__ __launch_bounds__(256) void rap_reduce(const float* __restrict__ partials,
                                                  float* __restrict__ outp) {
    const int q = blockIdx.x * blockDim.x + threadIdx.x;
    float s0 = 0.f, s1 = 0.f, s2 = 0.f, s3 = 0.f;
#pragma unroll 4
    for (int b = 0; b < NBLK; b += 4) {
        s0 += partials[(size_t)(b + 0) * Q_DIM + q];
        s1 += partials[(size_t)(b + 1) * Q_DIM + q];
        s2 += partials[(size_t)(b + 2) * Q_DIM + q];
        s3 += partials[(size_t)(b + 3) * Q_DIM + q];
    }
    outp[q] = ((s0 + s1) + (s2 + s3)) * (1.0f / N_DIM);
}

extern "C" void kernel_launch(void* const* d_in, const int* in_sizes, int n_in,
                              void* d_out, int out_size, void* d_ws, size_t ws_size,
                              hipStream_t stream) {
    const float* W    = (const float*)d_in[0];
    const int*   qidx = (const int*)d_in[1];
    float*       outp = (float*)d_out;

    const size_t need = (size_t)NBLK * Q_DIM * sizeof(float);
    if (ws_size >= need) {
        (void)hipFuncSetAttribute((const void*)rap_main<false>,
                                  hipFuncAttributeMaxDynamicSharedMemorySize, LDS_BYTES);
        float* partials = (float*)d_ws;
        hipLaunchKernelGGL(rap_main<false>, dim3(NBLK), dim3(TPB), LDS_BYTES, stream,
                           W, qidx, partials);
        hipLaunchKernelGGL(rap_reduce, dim3(Q_DIM / 256), dim3(256), 0, stream,
                           partials, outp);
    } else {
        (void)hipFuncSetAttribute((const void*)rap_main<true>,
                                  hipFuncAttributeMaxDynamicSharedMemorySize, LDS_BYTES);
        (void)hipMemsetAsync(d_out, 0, Q_DIM * sizeof(float), stream);
        hipLaunchKernelGGL(rap_main<true>, dim3(NBLK), dim3(TPB), LDS_BYTES, stream,
                           W, qidx, outp);
    }
}